// Round 9
// baseline (71.778 us; speedup 1.0000x reference)
//
#include <hip/hip_runtime.h>
#include <math.h>

#define NB 16
#define DIN 512
#define TT 4096
#define DCB 8
#define KC 1024
#define NW 8            // waves per block

// ws layout (floats):
// [0,4096)      w_inT[d][c]   (transposed)
// [4096,8192)   w_out[o][c]
// [8192,9216)   cb2[k]
// [9216,10240)  per-block commit partials (1024)

__global__ __launch_bounds__(512) void vq_setup(
    const float* __restrict__ in_v, const float* __restrict__ in_g,
    const float* __restrict__ out_v, const float* __restrict__ out_g,
    const float* __restrict__ cb, float* __restrict__ ws)
{
    int tid = threadIdx.x;
    float* w_inT = ws;
    float* w_out = ws + 4096;
    float* cb2   = ws + 8192;

    {   // w_in: 8 rows of 512; one wave per row
        int c    = tid >> 6;
        int lane = tid & 63;
        const float* v = in_v + c * DIN;
        float s = 0.f;
        #pragma unroll
        for (int i = 0; i < DIN; i += 64) {
            float x = v[i + lane];
            s += x * x;
        }
        #pragma unroll
        for (int off = 32; off > 0; off >>= 1) s += __shfl_xor(s, off, 64);
        float sq = sqrtf(s);
        float g  = in_g[c];
        #pragma unroll
        for (int i = 0; i < DIN; i += 64) {
            int d = i + lane;
            w_inT[d * DCB + c] = (g * v[d]) / sq;
        }
    }
    {   // w_out: 512 rows of 8
        int o = tid;
        const float* v = out_v + o * DCB;
        float s = 0.f;
        #pragma unroll
        for (int c = 0; c < DCB; ++c) s += v[c] * v[c];
        float sq = sqrtf(s);
        float g  = out_g[o];
        #pragma unroll
        for (int c = 0; c < DCB; ++c) w_out[o * DCB + c] = (g * v[c]) / sq;
    }
    for (int k = tid; k < KC; k += 512) {
        const float* r = cb + k * DCB;
        float s = 0.f;
        #pragma unroll
        for (int c = 0; c < DCB; ++c) s += r[c] * r[c];
        cb2[k] = s;
    }
}

// Fused main kernel. 1024 blocks x 512 threads; block = (b, 64-t chunk).
// wave w owns d in [64w,64w+64), k in [128w,128w+128), o in [64w,64w+64).
// s_buf is an OVERLAY: red partials (16 KB) until the reduce, then the
// codebook (32 KB). cb is prefetched into 16 VGPRs between in-proj and
// barrier(1) (short live range — r7's spill came from holding it across
// the in-proj loop). cb2/w_inT/w_out/out_b via wave-uniform s_load.
// LDS = 36.2 KB -> 4 blocks/CU; grid 1024 -> 8 waves/SIMD supply.
__global__ __launch_bounds__(512, 8) void vq_main(
    const float* __restrict__ z, const float* __restrict__ in_b,
    const float* __restrict__ out_b, const float* __restrict__ cb,
    const float* __restrict__ ws, float* __restrict__ ws_commit,
    float* __restrict__ out)
{
    __shared__ float s_buf[KC * DCB];    // 32 KB: red (first 16 KB) then cb[k][c]
    __shared__ float s_sd[NW][64];       // 2 KB
    __shared__ int   s_si[NW][64];       // 2 KB

    const float* w_inT = ws;
    const float* w_out = ws + 4096;
    const float* cb2w  = ws + 8192;

    int tid  = threadIdx.x;
    int w    = tid >> 6;
    int wu   = __builtin_amdgcn_readfirstlane(w);
    int lane = tid & 63;
    int blk  = blockIdx.x;               // 0..1023
    int b    = blk >> 6;
    int t    = (blk & 63) * 64 + lane;

    const float* zp = z + (size_t)b * DIN * TT + t;

    // ---- partial in-projection over d in [wu*64, wu*64+64) ----
    float ze[DCB];
    #pragma unroll
    for (int c = 0; c < DCB; ++c) ze[c] = 0.f;

    int d0 = wu * 64;
    #pragma unroll 4
    for (int dd = 0; dd < 64; ++dd) {
        int d = d0 + dd;
        float zv = zp[(size_t)d * TT];       // 256 B/wave, coalesced
        const float* wi = w_inT + d * DCB;   // uniform -> s_load_dwordx8
        #pragma unroll
        for (int c = 0; c < DCB; ++c) ze[c] = fmaf(wi[c], zv, ze[c]);
    }

    // ---- write red partials into s_buf[0,4096) ----
    float* redw = s_buf + w * (DCB * 64);
    #pragma unroll
    for (int c = 0; c < DCB; ++c) redw[c * 64 + lane] = ze[c];

    // ---- issue cb prefetch now (returns during reduce phase) ----
    float4 p0 = ((const float4*)cb)[tid];
    float4 p1 = ((const float4*)cb)[512 + tid];
    float4 p2 = ((const float4*)cb)[1024 + tid];
    float4 p3 = ((const float4*)cb)[1536 + tid];

    __syncthreads();   // (1) red visible

    // ---- cross-wave reduce of ze ----
    #pragma unroll
    for (int c = 0; c < DCB; ++c) {
        float s = 0.f;
        #pragma unroll
        for (int w2 = 0; w2 < NW; ++w2) s += s_buf[w2 * (DCB * 64) + c * 64 + lane];
        ze[c] = s + in_b[c];
    }
    __syncthreads();   // (2) red dead -> s_buf reusable

    // ---- overwrite s_buf with the codebook ----
    ((float4*)s_buf)[tid]        = p0;
    ((float4*)s_buf)[512 + tid]  = p1;
    ((float4*)s_buf)[1024 + tid] = p2;
    ((float4*)s_buf)[1536 + tid] = p3;
    __syncthreads();   // (3) cb visible

    float enc2 = 0.f;
    #pragma unroll
    for (int c = 0; c < DCB; ++c) enc2 += ze[c] * ze[c];

    // ---- codebook partial argmin over k in [wu*128, wu*128+128) ----
    float best = 3.4e38f;
    int   bi   = 0;
    int   k0   = wu * 128;
    #pragma unroll 4
    for (int kk = 0; kk < 128; ++kk) {
        int k = k0 + kk;
        float4 r0 = ((const float4*)s_buf)[2 * k];      // uniform -> broadcast
        float4 r1 = ((const float4*)s_buf)[2 * k + 1];
        float dot = fmaf(ze[0], r0.x, fmaf(ze[1], r0.y, fmaf(ze[2], r0.z, fmaf(ze[3], r0.w,
                    fmaf(ze[4], r1.x, fmaf(ze[5], r1.y, fmaf(ze[6], r1.z, ze[7] * r1.w)))))));
        float dk  = (enc2 - 2.0f * dot) + cb2w[k];      // cb2 uniform -> s_load
        if (dk < best) { best = dk; bi = k; }
    }
    s_sd[w][lane] = best;
    s_si[w][lane] = bi;
    __syncthreads();   // (4) sd/si visible

    // ---- ordered combine (w'=0..7, strict < keeps first min over k) ----
    float gbest = s_sd[0][lane];
    int   gbi   = s_si[0][lane];
    #pragma unroll
    for (int w2 = 1; w2 < NW; ++w2) {
        float d2 = s_sd[w2][lane];
        int   i2 = s_si[w2][lane];
        if (d2 < gbest) { gbest = d2; gbi = i2; }
    }

    // ---- z_q row from LDS ----
    float4 qa = ((const float4*)s_buf)[2 * gbi];
    float4 qb = ((const float4*)s_buf)[2 * gbi + 1];

    // ---- commit loss + indices: wave 0 ONLY ----
    if (wu == 0) {
        float cl = 0.f, f;
        f = ze[0]-qa.x; cl = fmaf(f,f,cl);
        f = ze[1]-qa.y; cl = fmaf(f,f,cl);
        f = ze[2]-qa.z; cl = fmaf(f,f,cl);
        f = ze[3]-qa.w; cl = fmaf(f,f,cl);
        f = ze[4]-qb.x; cl = fmaf(f,f,cl);
        f = ze[5]-qb.y; cl = fmaf(f,f,cl);
        f = ze[6]-qb.z; cl = fmaf(f,f,cl);
        f = ze[7]-qb.w; cl = fmaf(f,f,cl);
        #pragma unroll
        for (int off = 32; off > 0; off >>= 1) cl += __shfl_xor(cl, off, 64);
        if (lane == 0) ws_commit[blk] = cl;
        // indices (as float; whole out buffer is read as fp32)
        out[(size_t)NB * DIN * TT + NB + (size_t)b * TT + t] = (float)gbi;
    }

    // ---- out-projection over o in [wu*64, wu*64+64) ----
    float* outp = out + (size_t)b * DIN * TT + t;
    int o0 = wu * 64;
    #pragma unroll 4
    for (int oo = 0; oo < 64; ++oo) {
        int o = o0 + oo;
        const float* wo = w_out + o * DCB;   // uniform -> s_load_dwordx8
        float obias = out_b[o];              // uniform -> s_load
        float a = fmaf(wo[0], qa.x, fmaf(wo[1], qa.y, fmaf(wo[2], qa.z, fmaf(wo[3], qa.w,
                  fmaf(wo[4], qb.x, fmaf(wo[5], qb.y, fmaf(wo[6], qb.z, wo[7] * qb.w)))))));
        outp[(size_t)o * TT] = a + obias;    // 256 B/wave, coalesced
    }
}

__global__ __launch_bounds__(64) void vq_commit(
    const float* __restrict__ ws_commit, float* __restrict__ out)
{
    int b    = blockIdx.x;
    int lane = threadIdx.x;
    float s = ws_commit[b * 64 + lane];
    #pragma unroll
    for (int off = 32; off > 0; off >>= 1) s += __shfl_xor(s, off, 64);
    if (lane == 0)
        out[(size_t)NB * DIN * TT + b] = s * (1.0f / (DCB * TT));
}

extern "C" void kernel_launch(void* const* d_in, const int* in_sizes, int n_in,
                              void* d_out, int out_size, void* d_ws, size_t ws_size,
                              hipStream_t stream) {
    const float* z     = (const float*)d_in[0];
    const float* in_v  = (const float*)d_in[1];
    const float* in_g  = (const float*)d_in[2];
    const float* in_b  = (const float*)d_in[3];
    const float* out_v = (const float*)d_in[4];
    const float* out_g = (const float*)d_in[5];
    const float* out_b = (const float*)d_in[6];
    const float* cb    = (const float*)d_in[7];

    float* ws  = (float*)d_ws;
    float* out = (float*)d_out;

    vq_setup<<<1, 512, 0, stream>>>(in_v, in_g, out_v, out_g, cb, ws);
    vq_main<<<1024, 512, 0, stream>>>(z, in_b, out_b, cb, ws, ws + 9216, out);
    vq_commit<<<NB, 64, 0, stream>>>(ws + 9216, out);
}